// Round 1
// baseline (833.018 us; speedup 1.0000x reference)
//
#include <hip/hip_runtime.h>

#define TWO_PI 6.28318530717958647692f

constexpr int BB   = 32;     // batch
constexpr int NTOT = 16384;  // sequence length
constexpr int CKd  = 16;     // C*K channels
constexpr int NLEV = 14;     // log2(NTOT)

// ---------------------------------------------------------------------------
// Fused decomposition + truncated forward DFT.
// Input x (B, 2*nhalf, 16). Computes d = xa@ec_d, s = xa@ec_s rows, writes s
// to xout (B, nhalf, 16), and atomically accumulates the first l rfft modes of
// d and s into Fd/Fx (B,16,64,2).
// grid (B, ceil(nhalf/256)), block 256.
// ---------------------------------------------------------------------------
__global__ __launch_bounds__(256) void fwd_kernel(
    const float* __restrict__ xin, float* __restrict__ xout,
    float* __restrict__ Fd, float* __restrict__ Fx,
    const float* __restrict__ ec_s, const float* __restrict__ ec_d,
    int nhalf, int l)
{
  __shared__ float dt[256][20];   // pad 16->20 floats to spread LDS banks
  __shared__ float st[256][20];
  const int b   = blockIdx.x;
  const int t0  = blockIdx.y << 8;
  const int tid = threadIdx.x;
  const int rem = nhalf - t0;
  const int rows = rem < 256 ? rem : 256;
  const int t = t0 + tid;

  if (tid < rows) {
    const float* src = xin + ((size_t)b * (2 * (size_t)nhalf) + 2 * (size_t)t) * CKd;
    float xa[32];
#pragma unroll
    for (int q = 0; q < 8; ++q) {
      float4 v = reinterpret_cast<const float4*>(src)[q];
      xa[q*4+0] = v.x; xa[q*4+1] = v.y; xa[q*4+2] = v.z; xa[q*4+3] = v.w;
    }
    float srow[16];
#pragma unroll
    for (int c = 0; c < 4; ++c) {
#pragma unroll
      for (int j = 0; j < 4; ++j) {
        float ad = 0.f, as = 0.f;
#pragma unroll
        for (int m = 0; m < 4; ++m) {
          const float xe = xa[c*4+m];       // even sample coeffs
          const float xo = xa[16+c*4+m];    // odd sample coeffs
          ad += xe * ec_d[m*4+j] + xo * ec_d[(4+m)*4+j];
          as += xe * ec_s[m*4+j] + xo * ec_s[(4+m)*4+j];
        }
        dt[tid][c*4+j] = ad;
        st[tid][c*4+j] = as;
        srow[c*4+j]    = as;
      }
    }
    float4* dst = reinterpret_cast<float4*>(xout + ((size_t)b * nhalf + t) * CKd);
#pragma unroll
    for (int q = 0; q < 4; ++q)
      dst[q] = make_float4(srow[q*4], srow[q*4+1], srow[q*4+2], srow[q*4+3]);
  }
  __syncthreads();

  const int f = tid >> 2, g = tid & 3;
  if (f >= l) return;
  float dre[4] = {0,0,0,0}, dim_[4] = {0,0,0,0};
  float sre[4] = {0,0,0,0}, sim_[4] = {0,0,0,0};
  const int   mask = nhalf - 1;              // nhalf is a power of two
  const float w    = TWO_PI / (float)nhalf;
  for (int tt = 0; tt < rows; ++tt) {
    const int tg = t0 + tt;
    float sv, cv;
    __sincosf((float)((f * tg) & mask) * w, &sv, &cv);  // exact int range-reduce
    const float4 dv = *reinterpret_cast<const float4*>(&dt[tt][g*4]);
    const float4 xv = *reinterpret_cast<const float4*>(&st[tt][g*4]);
    const float dvv[4] = {dv.x, dv.y, dv.z, dv.w};
    const float xvv[4] = {xv.x, xv.y, xv.z, xv.w};
#pragma unroll
    for (int q = 0; q < 4; ++q) {
      dre[q] += dvv[q] * cv;  dim_[q] -= dvv[q] * sv;   // e^{-i theta}
      sre[q] += xvv[q] * cv;  sim_[q] -= xvv[q] * sv;
    }
  }
#pragma unroll
  for (int q = 0; q < 4; ++q) {
    const int i = g*4 + q;
    const int base = ((b * CKd + i) * 64 + f) * 2;
    atomicAdd(&Fd[base],   dre[q]);
    atomicAdd(&Fd[base+1], dim_[q]);
    atomicAdd(&Fx[base],   sre[q]);
    atomicAdd(&Fx[base+1], sim_[q]);
  }
}

// ---------------------------------------------------------------------------
// Complex channel mixing: Gud = Fd*wA + Fx*wB ; Gus = Fd*wC  (per mode f<l).
// grid (B, l), block 32: tid<16 -> Gud[o], tid>=16 -> Gus[o].
// ---------------------------------------------------------------------------
__global__ void mix_kernel(
    const float* __restrict__ Fd, const float* __restrict__ Fx,
    float* __restrict__ Gud, float* __restrict__ Gus,
    const float* __restrict__ wAre, const float* __restrict__ wAim,
    const float* __restrict__ wBre, const float* __restrict__ wBim,
    const float* __restrict__ wCre, const float* __restrict__ wCim)
{
  const int b = blockIdx.x;
  const int f = blockIdx.y;
  const int tid = threadIdx.x;
  const int o = tid & 15;
  const bool isUs = tid >= 16;
  float are = 0.f, aim = 0.f;
#pragma unroll 4
  for (int i = 0; i < 16; ++i) {
    const int fb = ((b * CKd + i) * 64 + f) * 2;
    const int wb = (i * CKd + o) * 64 + f;
    const float dre = Fd[fb], dim_ = Fd[fb+1];
    if (!isUs) {
      float wre = wAre[wb], wim = wAim[wb];
      are += dre * wre - dim_ * wim;
      aim += dre * wim + dim_ * wre;
      const float xre = Fx[fb], xim = Fx[fb+1];
      wre = wBre[wb]; wim = wBim[wb];
      are += xre * wre - xim * wim;
      aim += xre * wim + xim * wre;
    } else {
      const float wre = wCre[wb], wim = wCim[wb];
      are += dre * wre - dim_ * wim;
      aim += dre * wim + dim_ * wre;
    }
  }
  const int gb = ((b * CKd + o) * 64 + f) * 2;
  if (!isUs) { Gud[gb] = are; Gud[gb+1] = aim; }
  else       { Gus[gb] = are; Gus[gb+1] = aim; }
}

// ---------------------------------------------------------------------------
// Truncated inverse rfft for Gud and Gus simultaneously -> Ud, Us (B,n,16).
// numpy c2r semantics: imag of DC (and Nyquist when present) is dropped;
// Nyquist weight is 1, interior modes weight 2.
// grid (B, ceil(n/256)), block 256.
// ---------------------------------------------------------------------------
__global__ __launch_bounds__(256) void inv_kernel(
    const float* __restrict__ Gud, const float* __restrict__ Gus,
    float* __restrict__ Ud, float* __restrict__ Us, int n, int l)
{
  __shared__ float4 sG[64 * 16];   // [f][i] = (udRe, udIm, usRe, usIm)
  const int b = blockIdx.x;
  const int tid = threadIdx.x;
  for (int idx = tid; idx < l * 16; idx += 256) {
    const int f = idx >> 4, i = idx & 15;
    const int base = ((b * CKd + i) * 64 + f) * 2;
    sG[idx] = make_float4(Gud[base], Gud[base+1], Gus[base], Gus[base+1]);
  }
  __syncthreads();
  const int t = (blockIdx.y << 8) + tid;
  if (t >= n) return;

  float ud[16], us[16];
#pragma unroll
  for (int i = 0; i < 16; ++i) { const float4 g = sG[i]; ud[i] = g.x; us[i] = g.z; }

  const int   mask = n - 1;
  const float w    = TWO_PI / (float)n;
  for (int f = 1; f < l; ++f) {
    float sv, cv;
    __sincosf((float)((f * t) & mask) * w, &sv, &cv);
    const float scale = (2 * f == n) ? 1.f : 2.f;   // Nyquist weight
    cv *= scale; sv *= scale;
#pragma unroll
    for (int i = 0; i < 16; ++i) {
      const float4 g = sG[f * 16 + i];
      ud[i] += g.x * cv - g.y * sv;   // Re(G * e^{+i theta})
      us[i] += g.z * cv - g.w * sv;
    }
  }
  const float invn = 1.f / (float)n;
  const size_t ro = ((size_t)b * n + t) * CKd;
  float4* pud = reinterpret_cast<float4*>(Ud + ro);
  float4* pus = reinterpret_cast<float4*>(Us + ro);
#pragma unroll
  for (int q = 0; q < 4; ++q) {
    pud[q] = make_float4(ud[q*4]*invn, ud[q*4+1]*invn, ud[q*4+2]*invn, ud[q*4+3]*invn);
    pus[q] = make_float4(us[q*4]*invn, us[q*4+1]*invn, us[q*4+2]*invn, us[q*4+3]*invn);
  }
}

// ---------------------------------------------------------------------------
// Coarsest-scale linear map: x = x @ t0_w^T + t0_b  over last dim (K=4).
// x is (B, 1, 16). One thread per output element (512 total).
// ---------------------------------------------------------------------------
__global__ void t0_kernel(const float* __restrict__ xin, float* __restrict__ xout,
                          const float* __restrict__ t0w, const float* __restrict__ t0b)
{
  const int idx = blockIdx.x * 256 + threadIdx.x;
  if (idx >= BB * CKd) return;
  const int bc = idx >> 2;        // b*4 + c
  const int k  = idx & 3;
  float acc = t0b[k];
#pragma unroll
  for (int j = 0; j < 4; ++j) acc += xin[bc*4 + j] * t0w[k*4 + j];
  xout[idx] = acc;
}

// ---------------------------------------------------------------------------
// Reconstruction: x' = x + Us; xc = [x', Ud]; even = xc@rc_e, odd = xc@rc_o;
// interleave into xout (B, 2n, 16). One thread per (b,t).
// ---------------------------------------------------------------------------
__global__ __launch_bounds__(256) void recon_kernel(
    const float* __restrict__ xin, const float* __restrict__ UsL,
    const float* __restrict__ UdL, float* __restrict__ xout,
    int n, int lg, const float* __restrict__ rc_e, const float* __restrict__ rc_o)
{
  const int idx = blockIdx.x * 256 + threadIdx.x;
  if (idx >= BB * n) return;
  const int b = idx >> lg;
  const int t = idx & (n - 1);
  const size_t ro = ((size_t)b * n + t) * CKd;
  float xv[16], uv[16], dv[16];
#pragma unroll
  for (int q = 0; q < 4; ++q) {
    const float4 a = reinterpret_cast<const float4*>(xin + ro)[q];
    const float4 u = reinterpret_cast<const float4*>(UsL + ro)[q];
    const float4 d = reinterpret_cast<const float4*>(UdL + ro)[q];
    xv[q*4]=a.x; xv[q*4+1]=a.y; xv[q*4+2]=a.z; xv[q*4+3]=a.w;
    uv[q*4]=u.x; uv[q*4+1]=u.y; uv[q*4+2]=u.z; uv[q*4+3]=u.w;
    dv[q*4]=d.x; dv[q*4+1]=d.y; dv[q*4+2]=d.z; dv[q*4+3]=d.w;
  }
  float xe[16], xo[16];
#pragma unroll
  for (int c = 0; c < 4; ++c) {
    float xc[8];
#pragma unroll
    for (int m = 0; m < 4; ++m) { xc[m] = xv[c*4+m] + uv[c*4+m]; xc[4+m] = dv[c*4+m]; }
#pragma unroll
    for (int k = 0; k < 4; ++k) {
      float ae = 0.f, ao = 0.f;
#pragma unroll
      for (int m = 0; m < 8; ++m) { ae += xc[m] * rc_e[m*4+k]; ao += xc[m] * rc_o[m*4+k]; }
      xe[c*4+k] = ae; xo[c*4+k] = ao;
    }
  }
  float4* out = reinterpret_cast<float4*>(xout + ((size_t)b * (2*(size_t)n) + 2*(size_t)t) * CKd);
#pragma unroll
  for (int q = 0; q < 4; ++q) {
    out[q]   = make_float4(xe[q*4], xe[q*4+1], xe[q*4+2], xe[q*4+3]);
    out[4+q] = make_float4(xo[q*4], xo[q*4+1], xo[q*4+2], xo[q*4+3]);
  }
}

// ---------------------------------------------------------------------------
extern "C" void kernel_launch(void* const* d_in, const int* in_sizes, int n_in,
                              void* d_out, int out_size, void* d_ws, size_t ws_size,
                              hipStream_t stream)
{
  const float* x    = (const float*)d_in[0];
  const float* ec_s = (const float*)d_in[1];
  const float* ec_d = (const float*)d_in[2];
  const float* rc_e = (const float*)d_in[3];
  const float* rc_o = (const float*)d_in[4];
  const float* t0w  = (const float*)d_in[5];
  const float* t0b  = (const float*)d_in[6];
  const float* wAre = (const float*)d_in[7];
  const float* wAim = (const float*)d_in[8];
  const float* wBre = (const float*)d_in[9];
  const float* wBim = (const float*)d_in[10];
  const float* wCre = (const float*)d_in[11];
  const float* wCim = (const float*)d_in[12];

  float* ws = (float*)d_ws;
  const size_t XS_ELEMS = (size_t)BB * (NTOT/2) * CKd;   // 4,194,304
  const size_t U_ELEMS  = (size_t)BB * (NTOT - 1) * CKd; // 8,388,096 (sum of levels)
  const size_t F_ELEMS  = (size_t)BB * CKd * 64 * 2;     // 65,536
  float* xsA = ws;
  float* xsB = xsA + XS_ELEMS;
  float* UdS = xsB + XS_ELEMS;
  float* UsS = UdS + U_ELEMS;
  float* Fd  = UsS + U_ELEMS;
  float* Fx  = Fd + F_ELEMS;
  float* Gud = Fx + F_ELEMS;
  float* Gus = Gud + F_ELEMS;

  float* udl[NLEV]; float* usl[NLEV]; int nlv[NLEV];

  // ---- decomposition ----
  const float* cur = x;
  float* nxt = xsA;
  size_t uoff = 0;
  int nhalf = NTOT / 2;
  for (int j = 0; j < NLEV; ++j, nhalf >>= 1) {
    const int l = (nhalf/2 + 1 < 64) ? (nhalf/2 + 1) : 64;
    hipMemsetAsync(Fd, 0, F_ELEMS * sizeof(float), stream);
    hipMemsetAsync(Fx, 0, F_ELEMS * sizeof(float), stream);
    const int S = (nhalf + 255) / 256;
    fwd_kernel<<<dim3(BB, S), 256, 0, stream>>>(cur, nxt, Fd, Fx, ec_s, ec_d, nhalf, l);
    mix_kernel<<<dim3(BB, l), 32, 0, stream>>>(Fd, Fx, Gud, Gus,
                                               wAre, wAim, wBre, wBim, wCre, wCim);
    udl[j] = UdS + uoff; usl[j] = UsS + uoff; nlv[j] = nhalf;
    inv_kernel<<<dim3(BB, S), 256, 0, stream>>>(Gud, Gus, udl[j], usl[j], nhalf, l);
    uoff += (size_t)BB * nhalf * CKd;
    cur = nxt;
    nxt = (nxt == xsA) ? xsB : xsA;
  }

  // ---- coarsest-scale T0 ----
  t0_kernel<<<2, 256, 0, stream>>>(cur, nxt, t0w, t0b);
  cur = nxt;
  nxt = (nxt == xsA) ? xsB : xsA;

  // ---- reconstruction ----
  for (int i = NLEV - 1; i >= 0; --i) {
    const int n = nlv[i];
    int lg = 0; while ((1 << lg) < n) ++lg;
    float* out = (i == 0) ? (float*)d_out : nxt;
    const int total = BB * n;
    recon_kernel<<<(total + 255) / 256, 256, 0, stream>>>(cur, usl[i], udl[i], out,
                                                          n, lg, rc_e, rc_o);
    cur = out;
    nxt = (nxt == xsA) ? xsB : xsA;
  }
}

// Round 4
// 790.331 us; speedup vs baseline: 1.0540x; 1.0540x over previous
//
#include <hip/hip_runtime.h>

#define TWO_PI 6.28318530717958647692f

constexpr int BB   = 32;     // batch
constexpr int NTOT = 16384;  // sequence length
constexpr int CKd  = 16;     // C*K channels
constexpr int NLEV = 14;     // log2(NTOT)

// ===========================================================================
// NEW big-level kernels (nhalf >= 512, l == 64). Experimental arm of bisect.
// ===========================================================================
__device__ __forceinline__ void decomp_row(const float* __restrict__ src,
                                           const float* __restrict__ ec_s,
                                           const float* __restrict__ ec_d,
                                           float* d, float* s)
{
  float xa[32];
#pragma unroll
  for (int q = 0; q < 8; ++q) {
    float4 v = reinterpret_cast<const float4*>(src)[q];
    xa[q*4+0] = v.x; xa[q*4+1] = v.y; xa[q*4+2] = v.z; xa[q*4+3] = v.w;
  }
#pragma unroll
  for (int c = 0; c < 4; ++c) {
#pragma unroll
    for (int j = 0; j < 4; ++j) {
      float ad = 0.f, as = 0.f;
#pragma unroll
      for (int m = 0; m < 4; ++m) {
        const float xe = xa[c*4+m];
        const float xo = xa[16+c*4+m];
        ad += xe * ec_d[m*4+j] + xo * ec_d[(4+m)*4+j];
        as += xe * ec_s[m*4+j] + xo * ec_s[(4+m)*4+j];
      }
      d[c*4+j] = ad; s[c*4+j] = as;
    }
  }
}

// Fused decomposition + paired truncated forward DFT (radix-2 on time axis).
// grid (B, nhalf/512), block 256; all blocks full. nhalf >= 512.
__global__ __launch_bounds__(256) void fwd_big(
    const float* __restrict__ xin, float* __restrict__ xout,
    float* __restrict__ Fd, float* __restrict__ Fx,
    const float* __restrict__ ec_s, const float* __restrict__ ec_d,
    int nhalf)
{
  __shared__ float smem[16384];              // Pd,Md,Ps,Ms [256][16]
  float* Pd = smem;
  float* Md = smem + 4096;
  float* Ps = smem + 8192;
  float* Ms = smem + 12288;
  const int b    = blockIdx.x;
  const int t0p  = blockIdx.y << 8;
  const int tid  = threadIdx.x;
  const int halfn = nhalf >> 1;
  const int p    = t0p + tid;                // pair index < halfn

  float da[16], sa[16], db[16], sb[16];
  const size_t rowbase = (size_t)b * (2 * (size_t)nhalf) * CKd;
  decomp_row(xin + rowbase + (2*(size_t)p)*CKd,           ec_s, ec_d, da, sa);
  decomp_row(xin + rowbase + (2*(size_t)(p+halfn))*CKd,   ec_s, ec_d, db, sb);
  {
    float4* o0 = reinterpret_cast<float4*>(xout + ((size_t)b*nhalf + p)*CKd);
    float4* o1 = reinterpret_cast<float4*>(xout + ((size_t)b*nhalf + p + halfn)*CKd);
#pragma unroll
    for (int q = 0; q < 4; ++q) {
      o0[q] = make_float4(sa[q*4], sa[q*4+1], sa[q*4+2], sa[q*4+3]);
      o1[q] = make_float4(sb[q*4], sb[q*4+1], sb[q*4+2], sb[q*4+3]);
    }
  }
#pragma unroll
  for (int i = 0; i < 16; ++i) {
    Pd[tid*16+i] = da[i] + db[i];
    Md[tid*16+i] = da[i] - db[i];
    Ps[tid*16+i] = sa[i] + sb[i];
    Ms[tid*16+i] = sa[i] - sb[i];
  }
  __syncthreads();

  const int f = tid >> 2, g = tid & 3;       // f in [0,64)
  const float* srcd = (f & 1) ? Md : Pd;
  const float* srcs = (f & 1) ? Ms : Ps;
  const int   mask = nhalf - 1;
  const float w    = TWO_PI / (float)nhalf;
  float cv, sv, c1, s1;
  __sincosf((float)((f * t0p) & mask) * w, &sv, &cv);   // theta at p = t0p
  __sincosf((float)f * w, &s1, &c1);                    // step f*w
  float dre[4] = {0,0,0,0}, dim_[4] = {0,0,0,0};
  float sre[4] = {0,0,0,0}, sim_[4] = {0,0,0,0};
  for (int tt = 0; tt < 256; ++tt) {
    const float4 dv = *reinterpret_cast<const float4*>(srcd + tt*16 + g*4);
    const float4 xv = *reinterpret_cast<const float4*>(srcs + tt*16 + g*4);
    dre[0] += dv.x*cv; dim_[0] -= dv.x*sv;
    dre[1] += dv.y*cv; dim_[1] -= dv.y*sv;
    dre[2] += dv.z*cv; dim_[2] -= dv.z*sv;
    dre[3] += dv.w*cv; dim_[3] -= dv.w*sv;
    sre[0] += xv.x*cv; sim_[0] -= xv.x*sv;
    sre[1] += xv.y*cv; sim_[1] -= xv.y*sv;
    sre[2] += xv.z*cv; sim_[2] -= xv.z*sv;
    sre[3] += xv.w*cv; sim_[3] -= xv.w*sv;
    const float nc = cv*c1 - sv*s1;
    const float ns = sv*c1 + cv*s1;
    cv = nc; sv = ns;
  }
#pragma unroll
  for (int q = 0; q < 4; ++q) {
    const int i = g*4 + q;
    const int base = ((b * CKd + i) * 64 + f) * 2;
    atomicAdd(&Fd[base],   dre[q]);
    atomicAdd(&Fd[base+1], dim_[q]);
    atomicAdd(&Fx[base],   sre[q]);
    atomicAdd(&Fx[base+1], sim_[q]);
  }
}

// Mixing -> packed G4 (b,i,f,4)=(udRe,udIm,usRe,usIm). grid (B,64), block 32.
__global__ void mix_big(
    const float* __restrict__ Fd, const float* __restrict__ Fx,
    float* __restrict__ G4,
    const float* __restrict__ wAre, const float* __restrict__ wAim,
    const float* __restrict__ wBre, const float* __restrict__ wBim,
    const float* __restrict__ wCre, const float* __restrict__ wCim)
{
  const int b = blockIdx.x;
  const int f = blockIdx.y;
  const int tid = threadIdx.x;
  const int o = tid & 15;
  const bool isUs = tid >= 16;
  float are = 0.f, aim = 0.f;
#pragma unroll 4
  for (int i = 0; i < 16; ++i) {
    const int fb = ((b * CKd + i) * 64 + f) * 2;
    const int wb = (i * CKd + o) * 64 + f;
    const float dre = Fd[fb], dim_ = Fd[fb+1];
    if (!isUs) {
      float wre = wAre[wb], wim = wAim[wb];
      are += dre * wre - dim_ * wim;
      aim += dre * wim + dim_ * wre;
      const float xre = Fx[fb], xim = Fx[fb+1];
      wre = wBre[wb]; wim = wBim[wb];
      are += xre * wre - xim * wim;
      aim += xre * wim + xim * wre;
    } else {
      const float wre = wCre[wb], wim = wCim[wb];
      are += dre * wre - dim_ * wim;
      aim += dre * wim + dim_ * wre;
    }
  }
  float2* gp = reinterpret_cast<float2*>(G4 + ((size_t)(b * CKd + o) * 64 + f) * 4);
  gp[isUs ? 1 : 0] = make_float2(are, aim);
}

// LDS-free inverse truncated rfft, E/O radix-2 output symmetry.
// grid (B, n/512), block 256. n >= 512, l = 64, no Nyquist.
__global__ __launch_bounds__(256) void inv_big(
    const float* __restrict__ G4, float* __restrict__ Ud, float* __restrict__ Us,
    int n)
{
  const int b = blockIdx.x;
  const int t = (blockIdx.y << 8) + threadIdx.x;    // < n/2
  const int half = n >> 1;
  const float w = TWO_PI / (float)n;
  const float4* Gb = reinterpret_cast<const float4*>(G4) + (size_t)b * (CKd * 64);

  float udE[16], udO[16], usE[16], usO[16];
#pragma unroll
  for (int i = 0; i < 16; ++i) {
    const float4 g = Gb[i * 64];                    // f = 0 (DC)
    udE[i] = g.x; usE[i] = g.z; udO[i] = 0.f; usO[i] = 0.f;
  }
  float c1, s1;
  __sincosf((float)t * w, &s1, &c1);                // step e^{+i t w}
  float cv = c1, sv = s1;                           // f = 1
#pragma unroll 1
  for (int k = 0; k < 31; ++k) {
    {   // f = 2k+1 (odd)
      const float c2 = cv + cv, s2 = sv + sv;
      const int f = 2*k + 1;
#pragma unroll
      for (int i = 0; i < 16; ++i) {
        const float4 g = Gb[i*64 + f];
        udO[i] += g.x*c2 - g.y*s2;
        usO[i] += g.z*c2 - g.w*s2;
      }
      const float nc = cv*c1 - sv*s1, ns = sv*c1 + cv*s1; cv = nc; sv = ns;
    }
    {   // f = 2k+2 (even)
      const float c2 = cv + cv, s2 = sv + sv;
      const int f = 2*k + 2;
#pragma unroll
      for (int i = 0; i < 16; ++i) {
        const float4 g = Gb[i*64 + f];
        udE[i] += g.x*c2 - g.y*s2;
        usE[i] += g.z*c2 - g.w*s2;
      }
      const float nc = cv*c1 - sv*s1, ns = sv*c1 + cv*s1; cv = nc; sv = ns;
    }
  }
  {   // f = 63 (odd)
    const float c2 = cv + cv, s2 = sv + sv;
#pragma unroll
    for (int i = 0; i < 16; ++i) {
      const float4 g = Gb[i*64 + 63];
      udO[i] += g.x*c2 - g.y*s2;
      usO[i] += g.z*c2 - g.w*s2;
    }
  }
  const float invn = 1.f / (float)n;
  float4* u0 = reinterpret_cast<float4*>(Ud + ((size_t)b*n + t)*CKd);
  float4* u1 = reinterpret_cast<float4*>(Ud + ((size_t)b*n + t + half)*CKd);
  float4* v0 = reinterpret_cast<float4*>(Us + ((size_t)b*n + t)*CKd);
  float4* v1 = reinterpret_cast<float4*>(Us + ((size_t)b*n + t + half)*CKd);
#pragma unroll
  for (int q = 0; q < 4; ++q) {
    u0[q] = make_float4((udE[q*4+0]+udO[q*4+0])*invn, (udE[q*4+1]+udO[q*4+1])*invn,
                        (udE[q*4+2]+udO[q*4+2])*invn, (udE[q*4+3]+udO[q*4+3])*invn);
    u1[q] = make_float4((udE[q*4+0]-udO[q*4+0])*invn, (udE[q*4+1]-udO[q*4+1])*invn,
                        (udE[q*4+2]-udO[q*4+2])*invn, (udE[q*4+3]-udO[q*4+3])*invn);
    v0[q] = make_float4((usE[q*4+0]+usO[q*4+0])*invn, (usE[q*4+1]+usO[q*4+1])*invn,
                        (usE[q*4+2]+usO[q*4+2])*invn, (usE[q*4+3]+usO[q*4+3])*invn);
    v1[q] = make_float4((usE[q*4+0]-usO[q*4+0])*invn, (usE[q*4+1]-usO[q*4+1])*invn,
                        (usE[q*4+2]-usO[q*4+2])*invn, (usE[q*4+3]-usO[q*4+3])*invn);
  }
}

// ===========================================================================
// ROUND-1 VERBATIM kernels (proven passing) — used for small levels + recon.
// ===========================================================================
__global__ __launch_bounds__(256) void fwd_kernel(
    const float* __restrict__ xin, float* __restrict__ xout,
    float* __restrict__ Fd, float* __restrict__ Fx,
    const float* __restrict__ ec_s, const float* __restrict__ ec_d,
    int nhalf, int l)
{
  __shared__ float dt[256][20];
  __shared__ float st[256][20];
  const int b   = blockIdx.x;
  const int t0  = blockIdx.y << 8;
  const int tid = threadIdx.x;
  const int rem = nhalf - t0;
  const int rows = rem < 256 ? rem : 256;
  const int t = t0 + tid;

  if (tid < rows) {
    const float* src = xin + ((size_t)b * (2 * (size_t)nhalf) + 2 * (size_t)t) * CKd;
    float xa[32];
#pragma unroll
    for (int q = 0; q < 8; ++q) {
      float4 v = reinterpret_cast<const float4*>(src)[q];
      xa[q*4+0] = v.x; xa[q*4+1] = v.y; xa[q*4+2] = v.z; xa[q*4+3] = v.w;
    }
    float srow[16];
#pragma unroll
    for (int c = 0; c < 4; ++c) {
#pragma unroll
      for (int j = 0; j < 4; ++j) {
        float ad = 0.f, as = 0.f;
#pragma unroll
        for (int m = 0; m < 4; ++m) {
          const float xe = xa[c*4+m];
          const float xo = xa[16+c*4+m];
          ad += xe * ec_d[m*4+j] + xo * ec_d[(4+m)*4+j];
          as += xe * ec_s[m*4+j] + xo * ec_s[(4+m)*4+j];
        }
        dt[tid][c*4+j] = ad;
        st[tid][c*4+j] = as;
        srow[c*4+j]    = as;
      }
    }
    float4* dst = reinterpret_cast<float4*>(xout + ((size_t)b * nhalf + t) * CKd);
#pragma unroll
    for (int q = 0; q < 4; ++q)
      dst[q] = make_float4(srow[q*4], srow[q*4+1], srow[q*4+2], srow[q*4+3]);
  }
  __syncthreads();

  const int f = tid >> 2, g = tid & 3;
  if (f >= l) return;
  float dre[4] = {0,0,0,0}, dim_[4] = {0,0,0,0};
  float sre[4] = {0,0,0,0}, sim_[4] = {0,0,0,0};
  const int   mask = nhalf - 1;
  const float w    = TWO_PI / (float)nhalf;
  for (int tt = 0; tt < rows; ++tt) {
    const int tg = t0 + tt;
    float sv, cv;
    __sincosf((float)((f * tg) & mask) * w, &sv, &cv);
    const float4 dv = *reinterpret_cast<const float4*>(&dt[tt][g*4]);
    const float4 xv = *reinterpret_cast<const float4*>(&st[tt][g*4]);
    const float dvv[4] = {dv.x, dv.y, dv.z, dv.w};
    const float xvv[4] = {xv.x, xv.y, xv.z, xv.w};
#pragma unroll
    for (int q = 0; q < 4; ++q) {
      dre[q] += dvv[q] * cv;  dim_[q] -= dvv[q] * sv;
      sre[q] += xvv[q] * cv;  sim_[q] -= xvv[q] * sv;
    }
  }
#pragma unroll
  for (int q = 0; q < 4; ++q) {
    const int i = g*4 + q;
    const int base = ((b * CKd + i) * 64 + f) * 2;
    atomicAdd(&Fd[base],   dre[q]);
    atomicAdd(&Fd[base+1], dim_[q]);
    atomicAdd(&Fx[base],   sre[q]);
    atomicAdd(&Fx[base+1], sim_[q]);
  }
}

__global__ void mix_kernel(
    const float* __restrict__ Fd, const float* __restrict__ Fx,
    float* __restrict__ Gud, float* __restrict__ Gus,
    const float* __restrict__ wAre, const float* __restrict__ wAim,
    const float* __restrict__ wBre, const float* __restrict__ wBim,
    const float* __restrict__ wCre, const float* __restrict__ wCim)
{
  const int b = blockIdx.x;
  const int f = blockIdx.y;
  const int tid = threadIdx.x;
  const int o = tid & 15;
  const bool isUs = tid >= 16;
  float are = 0.f, aim = 0.f;
#pragma unroll 4
  for (int i = 0; i < 16; ++i) {
    const int fb = ((b * CKd + i) * 64 + f) * 2;
    const int wb = (i * CKd + o) * 64 + f;
    const float dre = Fd[fb], dim_ = Fd[fb+1];
    if (!isUs) {
      float wre = wAre[wb], wim = wAim[wb];
      are += dre * wre - dim_ * wim;
      aim += dre * wim + dim_ * wre;
      const float xre = Fx[fb], xim = Fx[fb+1];
      wre = wBre[wb]; wim = wBim[wb];
      are += xre * wre - xim * wim;
      aim += xre * wim + xim * wre;
    } else {
      const float wre = wCre[wb], wim = wCim[wb];
      are += dre * wre - dim_ * wim;
      aim += dre * wim + dim_ * wre;
    }
  }
  const int gb = ((b * CKd + o) * 64 + f) * 2;
  if (!isUs) { Gud[gb] = are; Gud[gb+1] = aim; }
  else       { Gus[gb] = are; Gus[gb+1] = aim; }
}

__global__ __launch_bounds__(256) void inv_kernel(
    const float* __restrict__ Gud, const float* __restrict__ Gus,
    float* __restrict__ Ud, float* __restrict__ Us, int n, int l)
{
  __shared__ float4 sG[64 * 16];
  const int b = blockIdx.x;
  const int tid = threadIdx.x;
  for (int idx = tid; idx < l * 16; idx += 256) {
    const int f = idx >> 4, i = idx & 15;
    const int base = ((b * CKd + i) * 64 + f) * 2;
    sG[idx] = make_float4(Gud[base], Gud[base+1], Gus[base], Gus[base+1]);
  }
  __syncthreads();
  const int t = (blockIdx.y << 8) + tid;
  if (t >= n) return;

  float ud[16], us[16];
#pragma unroll
  for (int i = 0; i < 16; ++i) { const float4 g = sG[i]; ud[i] = g.x; us[i] = g.z; }

  const int   mask = n - 1;
  const float w    = TWO_PI / (float)n;
  for (int f = 1; f < l; ++f) {
    float sv, cv;
    __sincosf((float)((f * t) & mask) * w, &sv, &cv);
    const float scale = (2 * f == n) ? 1.f : 2.f;
    cv *= scale; sv *= scale;
#pragma unroll
    for (int i = 0; i < 16; ++i) {
      const float4 g = sG[f * 16 + i];
      ud[i] += g.x * cv - g.y * sv;
      us[i] += g.z * cv - g.w * sv;
    }
  }
  const float invn = 1.f / (float)n;
  const size_t ro = ((size_t)b * n + t) * CKd;
  float4* pud = reinterpret_cast<float4*>(Ud + ro);
  float4* pus = reinterpret_cast<float4*>(Us + ro);
#pragma unroll
  for (int q = 0; q < 4; ++q) {
    pud[q] = make_float4(ud[q*4]*invn, ud[q*4+1]*invn, ud[q*4+2]*invn, ud[q*4+3]*invn);
    pus[q] = make_float4(us[q*4]*invn, us[q*4+1]*invn, us[q*4+2]*invn, us[q*4+3]*invn);
  }
}

__global__ void t0_kernel(const float* __restrict__ xin, float* __restrict__ xout,
                          const float* __restrict__ t0w, const float* __restrict__ t0b)
{
  const int idx = blockIdx.x * 256 + threadIdx.x;
  if (idx >= BB * CKd) return;
  const int bc = idx >> 2;
  const int k  = idx & 3;
  float acc = t0b[k];
#pragma unroll
  for (int j = 0; j < 4; ++j) acc += xin[bc*4 + j] * t0w[k*4 + j];
  xout[idx] = acc;
}

__global__ __launch_bounds__(256) void recon_kernel(
    const float* __restrict__ xin, const float* __restrict__ UsL,
    const float* __restrict__ UdL, float* __restrict__ xout,
    int n, int lg, const float* __restrict__ rc_e, const float* __restrict__ rc_o)
{
  const int idx = blockIdx.x * 256 + threadIdx.x;
  if (idx >= BB * n) return;
  const int b = idx >> lg;
  const int t = idx & (n - 1);
  const size_t ro = ((size_t)b * n + t) * CKd;
  float xv[16], uv[16], dv[16];
#pragma unroll
  for (int q = 0; q < 4; ++q) {
    const float4 a = reinterpret_cast<const float4*>(xin + ro)[q];
    const float4 u = reinterpret_cast<const float4*>(UsL + ro)[q];
    const float4 d = reinterpret_cast<const float4*>(UdL + ro)[q];
    xv[q*4]=a.x; xv[q*4+1]=a.y; xv[q*4+2]=a.z; xv[q*4+3]=a.w;
    uv[q*4]=u.x; uv[q*4+1]=u.y; uv[q*4+2]=u.z; uv[q*4+3]=u.w;
    dv[q*4]=d.x; dv[q*4+1]=d.y; dv[q*4+2]=d.z; dv[q*4+3]=d.w;
  }
  float xe[16], xo[16];
#pragma unroll
  for (int c = 0; c < 4; ++c) {
    float xc[8];
#pragma unroll
    for (int m = 0; m < 4; ++m) { xc[m] = xv[c*4+m] + uv[c*4+m]; xc[4+m] = dv[c*4+m]; }
#pragma unroll
    for (int k = 0; k < 4; ++k) {
      float ae = 0.f, ao = 0.f;
#pragma unroll
      for (int m = 0; m < 8; ++m) { ae += xc[m] * rc_e[m*4+k]; ao += xc[m] * rc_o[m*4+k]; }
      xe[c*4+k] = ae; xo[c*4+k] = ao;
    }
  }
  float4* out = reinterpret_cast<float4*>(xout + ((size_t)b * (2*(size_t)n) + 2*(size_t)t) * CKd);
#pragma unroll
  for (int q = 0; q < 4; ++q) {
    out[q]   = make_float4(xe[q*4], xe[q*4+1], xe[q*4+2], xe[q*4+3]);
    out[4+q] = make_float4(xo[q*4], xo[q*4+1], xo[q*4+2], xo[q*4+3]);
  }
}

// ---------------------------------------------------------------------------
extern "C" void kernel_launch(void* const* d_in, const int* in_sizes, int n_in,
                              void* d_out, int out_size, void* d_ws, size_t ws_size,
                              hipStream_t stream)
{
  const float* x    = (const float*)d_in[0];
  const float* ec_s = (const float*)d_in[1];
  const float* ec_d = (const float*)d_in[2];
  const float* rc_e = (const float*)d_in[3];
  const float* rc_o = (const float*)d_in[4];
  const float* t0w  = (const float*)d_in[5];
  const float* t0b  = (const float*)d_in[6];
  const float* wAre = (const float*)d_in[7];
  const float* wAim = (const float*)d_in[8];
  const float* wBre = (const float*)d_in[9];
  const float* wBim = (const float*)d_in[10];
  const float* wCre = (const float*)d_in[11];
  const float* wCim = (const float*)d_in[12];

  float* ws = (float*)d_ws;
  const size_t XS_ELEMS = (size_t)BB * (NTOT/2) * CKd;   // 4,194,304
  const size_t U_ELEMS  = (size_t)BB * (NTOT - 1) * CKd; // 8,388,096
  const size_t F_ELEMS  = (size_t)BB * CKd * 64 * 2;     // 65,536
  float* xsA = ws;
  float* xsB = xsA + XS_ELEMS;
  float* UdS = xsB + XS_ELEMS;
  float* UsS = UdS + U_ELEMS;
  float* Fd  = UsS + U_ELEMS;
  float* Fx  = Fd + F_ELEMS;
  float* Gud = Fx + F_ELEMS;
  float* Gus = Gud + F_ELEMS;
  float* G4  = Gud;            // big path: G4 (2*F_ELEMS) aliases Gud+Gus

  float* udl[NLEV]; float* usl[NLEV]; int nlv[NLEV];

  // ---- decomposition ----
  const float* cur = x;
  float* nxt = xsA;
  size_t uoff = 0;
  int nhalf = NTOT / 2;
  for (int j = 0; j < NLEV; ++j, nhalf >>= 1) {
    const int l = (nhalf/2 + 1 < 64) ? (nhalf/2 + 1) : 64;
    hipMemsetAsync(Fd, 0, 2 * F_ELEMS * sizeof(float), stream);   // Fd+Fx contiguous
    udl[j] = UdS + uoff; usl[j] = UsS + uoff; nlv[j] = nhalf;
    if (nhalf >= 512) {
      fwd_big<<<dim3(BB, nhalf/512), 256, 0, stream>>>(cur, nxt, Fd, Fx, ec_s, ec_d, nhalf);
      mix_big<<<dim3(BB, 64), 32, 0, stream>>>(Fd, Fx, G4,
                                               wAre, wAim, wBre, wBim, wCre, wCim);
      inv_big<<<dim3(BB, nhalf/512), 256, 0, stream>>>(G4, udl[j], usl[j], nhalf);
    } else {
      const int S = (nhalf + 255) / 256;   // == 1 here
      fwd_kernel<<<dim3(BB, S), 256, 0, stream>>>(cur, nxt, Fd, Fx, ec_s, ec_d, nhalf, l);
      mix_kernel<<<dim3(BB, l), 32, 0, stream>>>(Fd, Fx, Gud, Gus,
                                                 wAre, wAim, wBre, wBim, wCre, wCim);
      inv_kernel<<<dim3(BB, S), 256, 0, stream>>>(Gud, Gus, udl[j], usl[j], nhalf, l);
    }
    uoff += (size_t)BB * nhalf * CKd;
    cur = nxt;
    nxt = (nxt == xsA) ? xsB : xsA;
  }

  // ---- coarsest-scale T0 ----
  t0_kernel<<<2, 256, 0, stream>>>(cur, nxt, t0w, t0b);
  cur = nxt;
  nxt = (nxt == xsA) ? xsB : xsA;

  // ---- reconstruction ----
  for (int i = NLEV - 1; i >= 0; --i) {
    const int n = nlv[i];
    int lg = 0; while ((1 << lg) < n) ++lg;
    float* out = (i == 0) ? (float*)d_out : nxt;
    const int total = BB * n;
    recon_kernel<<<(total + 255) / 256, 256, 0, stream>>>(cur, usl[i], udl[i], out,
                                                          n, lg, rc_e, rc_o);
    cur = out;
    nxt = (nxt == xsA) ? xsB : xsA;
  }
}

// Round 5
// 680.083 us; speedup vs baseline: 1.2249x; 1.1621x over previous
//
#include <hip/hip_runtime.h>

#define TWO_PI 6.28318530717958647692f

constexpr int BB   = 32;     // batch
constexpr int NTOT = 16384;  // sequence length
constexpr int CKd  = 16;     // C*K channels
constexpr int NLEV = 14;     // log2(NTOT)

// ===========================================================================
// BIG-level kernels (nhalf >= 512, l == 64).
// ===========================================================================
__device__ __forceinline__ void decomp_row(const float* __restrict__ src,
                                           const float* __restrict__ ec_s,
                                           const float* __restrict__ ec_d,
                                           float* d, float* s)
{
  float xa[32];
#pragma unroll
  for (int q = 0; q < 8; ++q) {
    float4 v = reinterpret_cast<const float4*>(src)[q];
    xa[q*4+0] = v.x; xa[q*4+1] = v.y; xa[q*4+2] = v.z; xa[q*4+3] = v.w;
  }
#pragma unroll
  for (int c = 0; c < 4; ++c) {
#pragma unroll
    for (int j = 0; j < 4; ++j) {
      float ad = 0.f, as = 0.f;
#pragma unroll
      for (int m = 0; m < 4; ++m) {
        const float xe = xa[c*4+m];
        const float xo = xa[16+c*4+m];
        ad += xe * ec_d[m*4+j] + xo * ec_d[(4+m)*4+j];
        as += xe * ec_s[m*4+j] + xo * ec_s[(4+m)*4+j];
      }
      d[c*4+j] = ad; s[c*4+j] = as;
    }
  }
}

// Fused decomposition + paired truncated forward DFT (radix-2 on time axis).
// grid (B, nhalf/512), block 256; all blocks full. nhalf >= 512.
__global__ __launch_bounds__(256) void fwd_big(
    const float* __restrict__ xin, float* __restrict__ xout,
    float* __restrict__ Fd, float* __restrict__ Fx,
    const float* __restrict__ ec_s, const float* __restrict__ ec_d,
    int nhalf)
{
  __shared__ float smem[16384];              // Pd,Md,Ps,Ms [256][16]
  float* Pd = smem;
  float* Md = smem + 4096;
  float* Ps = smem + 8192;
  float* Ms = smem + 12288;
  const int b    = blockIdx.x;
  const int t0p  = blockIdx.y << 8;
  const int tid  = threadIdx.x;
  const int halfn = nhalf >> 1;
  const int p    = t0p + tid;                // pair index < halfn

  float da[16], sa[16], db[16], sb[16];
  const size_t rowbase = (size_t)b * (2 * (size_t)nhalf) * CKd;
  decomp_row(xin + rowbase + (2*(size_t)p)*CKd,           ec_s, ec_d, da, sa);
  decomp_row(xin + rowbase + (2*(size_t)(p+halfn))*CKd,   ec_s, ec_d, db, sb);
  {
    float4* o0 = reinterpret_cast<float4*>(xout + ((size_t)b*nhalf + p)*CKd);
    float4* o1 = reinterpret_cast<float4*>(xout + ((size_t)b*nhalf + p + halfn)*CKd);
#pragma unroll
    for (int q = 0; q < 4; ++q) {
      o0[q] = make_float4(sa[q*4], sa[q*4+1], sa[q*4+2], sa[q*4+3]);
      o1[q] = make_float4(sb[q*4], sb[q*4+1], sb[q*4+2], sb[q*4+3]);
    }
  }
#pragma unroll
  for (int i = 0; i < 16; ++i) {
    Pd[tid*16+i] = da[i] + db[i];
    Md[tid*16+i] = da[i] - db[i];
    Ps[tid*16+i] = sa[i] + sb[i];
    Ms[tid*16+i] = sa[i] - sb[i];
  }
  __syncthreads();

  const int f = tid >> 2, g = tid & 3;       // f in [0,64)
  const float* srcd = (f & 1) ? Md : Pd;
  const float* srcs = (f & 1) ? Ms : Ps;
  const int   mask = nhalf - 1;
  const float w    = TWO_PI / (float)nhalf;
  float cv, sv, c1, s1;
  __sincosf((float)((f * t0p) & mask) * w, &sv, &cv);   // theta at p = t0p
  __sincosf((float)f * w, &s1, &c1);                    // step f*w
  float dre[4] = {0,0,0,0}, dim_[4] = {0,0,0,0};
  float sre[4] = {0,0,0,0}, sim_[4] = {0,0,0,0};
  for (int tt = 0; tt < 256; ++tt) {
    const float4 dv = *reinterpret_cast<const float4*>(srcd + tt*16 + g*4);
    const float4 xv = *reinterpret_cast<const float4*>(srcs + tt*16 + g*4);
    dre[0] += dv.x*cv; dim_[0] -= dv.x*sv;
    dre[1] += dv.y*cv; dim_[1] -= dv.y*sv;
    dre[2] += dv.z*cv; dim_[2] -= dv.z*sv;
    dre[3] += dv.w*cv; dim_[3] -= dv.w*sv;
    sre[0] += xv.x*cv; sim_[0] -= xv.x*sv;
    sre[1] += xv.y*cv; sim_[1] -= xv.y*sv;
    sre[2] += xv.z*cv; sim_[2] -= xv.z*sv;
    sre[3] += xv.w*cv; sim_[3] -= xv.w*sv;
    const float nc = cv*c1 - sv*s1;
    const float ns = sv*c1 + cv*s1;
    cv = nc; sv = ns;
  }
#pragma unroll
  for (int q = 0; q < 4; ++q) {
    const int i = g*4 + q;
    const int base = ((b * CKd + i) * 64 + f) * 2;
    atomicAdd(&Fd[base],   dre[q]);
    atomicAdd(&Fd[base+1], dim_[q]);
    atomicAdd(&Fx[base],   sre[q]);
    atomicAdd(&Fx[base+1], sim_[q]);
  }
}

// Mixing -> packed G4 (b,i,f,4)=(udRe,udIm,usRe,usIm). grid (B,64), block 32.
// Also zeros the consumed Fd/Fx slice so the next level's atomics start clean.
__global__ void mix_big(
    float* __restrict__ Fd, float* __restrict__ Fx,
    float* __restrict__ G4,
    const float* __restrict__ wAre, const float* __restrict__ wAim,
    const float* __restrict__ wBre, const float* __restrict__ wBim,
    const float* __restrict__ wCre, const float* __restrict__ wCim)
{
  const int b = blockIdx.x;
  const int f = blockIdx.y;
  const int tid = threadIdx.x;
  const int o = tid & 15;
  const bool isUs = tid >= 16;
  float are = 0.f, aim = 0.f;
#pragma unroll 4
  for (int i = 0; i < 16; ++i) {
    const int fb = ((b * CKd + i) * 64 + f) * 2;
    const int wb = (i * CKd + o) * 64 + f;
    const float dre = Fd[fb], dim_ = Fd[fb+1];
    if (!isUs) {
      float wre = wAre[wb], wim = wAim[wb];
      are += dre * wre - dim_ * wim;
      aim += dre * wim + dim_ * wre;
      const float xre = Fx[fb], xim = Fx[fb+1];
      wre = wBre[wb]; wim = wBim[wb];
      are += xre * wre - xim * wim;
      aim += xre * wim + xim * wre;
    } else {
      const float wre = wCre[wb], wim = wCim[wb];
      are += dre * wre - dim_ * wim;
      aim += dre * wim + dim_ * wre;
    }
  }
  float2* gp = reinterpret_cast<float2*>(G4 + ((size_t)(b * CKd + o) * 64 + f) * 4);
  gp[isUs ? 1 : 0] = make_float2(are, aim);
  __syncthreads();   // single wave: reads above are already done; belt&braces
  {
    const int zb = ((b * CKd + o) * 64 + f) * 2;
    float* dst = isUs ? &Fx[zb] : &Fd[zb];
    dst[0] = 0.f; dst[1] = 0.f;
  }
}

// Channel-per-lane inverse truncated rfft (l=64, no Nyquist), E/O radix-2
// output symmetry. lane&15 = channel, each thread owns 4 t-pairs (stride 16).
// G staged to LDS once per block ([f][i] layout, +1 float4 pad, x2 weight
// pre-folded) -> ONE ds_read_b128 per wave per mode. grid (B, n/128), blk 256.
__global__ __launch_bounds__(256) void inv_big(
    const float* __restrict__ G4, float* __restrict__ Ud, float* __restrict__ Us,
    int n)
{
  __shared__ float4 gl[64 * 17];             // [f][i] padded: idx = f*17+i
  const int b   = blockIdx.x;
  const int tid = threadIdx.x;
  const float4* Gb = reinterpret_cast<const float4*>(G4) + (size_t)b * 1024;
  for (int s_ = tid; s_ < 1024; s_ += 256) {
    const int i = s_ >> 6, f = s_ & 63;      // source-major: coalesced global read
    float4 v = Gb[(size_t)i * 64 + f];
    if (f) { v.x *= 2.f; v.y *= 2.f; v.z *= 2.f; v.w *= 2.f; }   // mode weight
    gl[f*17 + i] = v;
  }
  __syncthreads();

  const int i   = tid & 15;                  // channel
  const int col = tid >> 4;                  // t-column within block
  const int tb  = (blockIdx.y << 6) + col;   // t-pair base; thread t's: tb+16k
  const float w = TWO_PI / (float)n;

  float udE[4], udO[4], usE[4], usO[4], c[4], s[4], c1[4], s1[4];
  {
    const float4 g0 = gl[i];                 // f = 0 (DC, weight 1)
#pragma unroll
    for (int k = 0; k < 4; ++k) {
      udE[k] = g0.x; usE[k] = g0.z; udO[k] = 0.f; usO[k] = 0.f;
      __sincosf((float)(tb + 16*k) * w, &s1[k], &c1[k]);   // step e^{+i t w}
      c[k] = c1[k]; s[k] = s1[k];            // f = 1
    }
  }
#pragma unroll 1
  for (int kk = 0; kk < 31; ++kk) {
    {
      const float4 g = gl[(2*kk+1)*17 + i];  // f odd
#pragma unroll
      for (int k = 0; k < 4; ++k) {
        udO[k] += g.x*c[k] - g.y*s[k];
        usO[k] += g.z*c[k] - g.w*s[k];
        const float nc = c[k]*c1[k] - s[k]*s1[k];
        const float ns = s[k]*c1[k] + c[k]*s1[k];
        c[k] = nc; s[k] = ns;
      }
    }
    {
      const float4 g = gl[(2*kk+2)*17 + i];  // f even
#pragma unroll
      for (int k = 0; k < 4; ++k) {
        udE[k] += g.x*c[k] - g.y*s[k];
        usE[k] += g.z*c[k] - g.w*s[k];
        const float nc = c[k]*c1[k] - s[k]*s1[k];
        const float ns = s[k]*c1[k] + c[k]*s1[k];
        c[k] = nc; s[k] = ns;
      }
    }
  }
  {
    const float4 g = gl[63*17 + i];          // f = 63 (odd)
#pragma unroll
    for (int k = 0; k < 4; ++k) {
      udO[k] += g.x*c[k] - g.y*s[k];
      usO[k] += g.z*c[k] - g.w*s[k];
    }
  }
  const float invn = 1.f / (float)n;
  const int   half = n >> 1;
#pragma unroll
  for (int k = 0; k < 4; ++k) {
    const int t = tb + 16*k;
    const size_t r0 = ((size_t)b*n + t) * CKd + i;
    const size_t r1 = r0 + (size_t)half * CKd;
    Ud[r0] = (udE[k] + udO[k]) * invn;
    Ud[r1] = (udE[k] - udO[k]) * invn;
    Us[r0] = (usE[k] + usO[k]) * invn;
    Us[r1] = (usE[k] - usO[k]) * invn;
  }
}

// ===========================================================================
// Small-level kernels (verbatim-proven) + recon/t0.
// ===========================================================================
__global__ __launch_bounds__(256) void fwd_kernel(
    const float* __restrict__ xin, float* __restrict__ xout,
    float* __restrict__ Fd, float* __restrict__ Fx,
    const float* __restrict__ ec_s, const float* __restrict__ ec_d,
    int nhalf, int l)
{
  __shared__ float dt[256][20];
  __shared__ float st[256][20];
  const int b   = blockIdx.x;
  const int t0  = blockIdx.y << 8;
  const int tid = threadIdx.x;
  const int rem = nhalf - t0;
  const int rows = rem < 256 ? rem : 256;
  const int t = t0 + tid;

  if (tid < rows) {
    const float* src = xin + ((size_t)b * (2 * (size_t)nhalf) + 2 * (size_t)t) * CKd;
    float xa[32];
#pragma unroll
    for (int q = 0; q < 8; ++q) {
      float4 v = reinterpret_cast<const float4*>(src)[q];
      xa[q*4+0] = v.x; xa[q*4+1] = v.y; xa[q*4+2] = v.z; xa[q*4+3] = v.w;
    }
    float srow[16];
#pragma unroll
    for (int c = 0; c < 4; ++c) {
#pragma unroll
      for (int j = 0; j < 4; ++j) {
        float ad = 0.f, as = 0.f;
#pragma unroll
        for (int m = 0; m < 4; ++m) {
          const float xe = xa[c*4+m];
          const float xo = xa[16+c*4+m];
          ad += xe * ec_d[m*4+j] + xo * ec_d[(4+m)*4+j];
          as += xe * ec_s[m*4+j] + xo * ec_s[(4+m)*4+j];
        }
        dt[tid][c*4+j] = ad;
        st[tid][c*4+j] = as;
        srow[c*4+j]    = as;
      }
    }
    float4* dst = reinterpret_cast<float4*>(xout + ((size_t)b * nhalf + t) * CKd);
#pragma unroll
    for (int q = 0; q < 4; ++q)
      dst[q] = make_float4(srow[q*4], srow[q*4+1], srow[q*4+2], srow[q*4+3]);
  }
  __syncthreads();

  const int f = tid >> 2, g = tid & 3;
  if (f >= l) return;
  float dre[4] = {0,0,0,0}, dim_[4] = {0,0,0,0};
  float sre[4] = {0,0,0,0}, sim_[4] = {0,0,0,0};
  const int   mask = nhalf - 1;
  const float w    = TWO_PI / (float)nhalf;
  for (int tt = 0; tt < rows; ++tt) {
    const int tg = t0 + tt;
    float sv, cv;
    __sincosf((float)((f * tg) & mask) * w, &sv, &cv);
    const float4 dv = *reinterpret_cast<const float4*>(&dt[tt][g*4]);
    const float4 xv = *reinterpret_cast<const float4*>(&st[tt][g*4]);
    const float dvv[4] = {dv.x, dv.y, dv.z, dv.w};
    const float xvv[4] = {xv.x, xv.y, xv.z, xv.w};
#pragma unroll
    for (int q = 0; q < 4; ++q) {
      dre[q] += dvv[q] * cv;  dim_[q] -= dvv[q] * sv;
      sre[q] += xvv[q] * cv;  sim_[q] -= xvv[q] * sv;
    }
  }
#pragma unroll
  for (int q = 0; q < 4; ++q) {
    const int i = g*4 + q;
    const int base = ((b * CKd + i) * 64 + f) * 2;
    atomicAdd(&Fd[base],   dre[q]);
    atomicAdd(&Fd[base+1], dim_[q]);
    atomicAdd(&Fx[base],   sre[q]);
    atomicAdd(&Fx[base+1], sim_[q]);
  }
}

__global__ void mix_kernel(
    float* __restrict__ Fd, float* __restrict__ Fx,
    float* __restrict__ Gud, float* __restrict__ Gus,
    const float* __restrict__ wAre, const float* __restrict__ wAim,
    const float* __restrict__ wBre, const float* __restrict__ wBim,
    const float* __restrict__ wCre, const float* __restrict__ wCim)
{
  const int b = blockIdx.x;
  const int f = blockIdx.y;
  const int tid = threadIdx.x;
  const int o = tid & 15;
  const bool isUs = tid >= 16;
  float are = 0.f, aim = 0.f;
#pragma unroll 4
  for (int i = 0; i < 16; ++i) {
    const int fb = ((b * CKd + i) * 64 + f) * 2;
    const int wb = (i * CKd + o) * 64 + f;
    const float dre = Fd[fb], dim_ = Fd[fb+1];
    if (!isUs) {
      float wre = wAre[wb], wim = wAim[wb];
      are += dre * wre - dim_ * wim;
      aim += dre * wim + dim_ * wre;
      const float xre = Fx[fb], xim = Fx[fb+1];
      wre = wBre[wb]; wim = wBim[wb];
      are += xre * wre - xim * wim;
      aim += xre * wim + xim * wre;
    } else {
      const float wre = wCre[wb], wim = wCim[wb];
      are += dre * wre - dim_ * wim;
      aim += dre * wim + dim_ * wre;
    }
  }
  const int gb = ((b * CKd + o) * 64 + f) * 2;
  if (!isUs) { Gud[gb] = are; Gud[gb+1] = aim; }
  else       { Gus[gb] = are; Gus[gb+1] = aim; }
  __syncthreads();
  {
    const int zb = ((b * CKd + o) * 64 + f) * 2;
    float* dst = isUs ? &Fx[zb] : &Fd[zb];
    dst[0] = 0.f; dst[1] = 0.f;
  }
}

__global__ __launch_bounds__(256) void inv_kernel(
    const float* __restrict__ Gud, const float* __restrict__ Gus,
    float* __restrict__ Ud, float* __restrict__ Us, int n, int l)
{
  __shared__ float4 sG[64 * 16];
  const int b = blockIdx.x;
  const int tid = threadIdx.x;
  for (int idx = tid; idx < l * 16; idx += 256) {
    const int f = idx >> 4, i = idx & 15;
    const int base = ((b * CKd + i) * 64 + f) * 2;
    sG[idx] = make_float4(Gud[base], Gud[base+1], Gus[base], Gus[base+1]);
  }
  __syncthreads();
  const int t = (blockIdx.y << 8) + tid;
  if (t >= n) return;

  float ud[16], us[16];
#pragma unroll
  for (int i = 0; i < 16; ++i) { const float4 g = sG[i]; ud[i] = g.x; us[i] = g.z; }

  const int   mask = n - 1;
  const float w    = TWO_PI / (float)n;
  for (int f = 1; f < l; ++f) {
    float sv, cv;
    __sincosf((float)((f * t) & mask) * w, &sv, &cv);
    const float scale = (2 * f == n) ? 1.f : 2.f;
    cv *= scale; sv *= scale;
#pragma unroll
    for (int i = 0; i < 16; ++i) {
      const float4 g = sG[f * 16 + i];
      ud[i] += g.x * cv - g.y * sv;
      us[i] += g.z * cv - g.w * sv;
    }
  }
  const float invn = 1.f / (float)n;
  const size_t ro = ((size_t)b * n + t) * CKd;
  float4* pud = reinterpret_cast<float4*>(Ud + ro);
  float4* pus = reinterpret_cast<float4*>(Us + ro);
#pragma unroll
  for (int q = 0; q < 4; ++q) {
    pud[q] = make_float4(ud[q*4]*invn, ud[q*4+1]*invn, ud[q*4+2]*invn, ud[q*4+3]*invn);
    pus[q] = make_float4(us[q*4]*invn, us[q*4+1]*invn, us[q*4+2]*invn, us[q*4+3]*invn);
  }
}

__global__ void t0_kernel(const float* __restrict__ xin, float* __restrict__ xout,
                          const float* __restrict__ t0w, const float* __restrict__ t0b)
{
  const int idx = blockIdx.x * 256 + threadIdx.x;
  if (idx >= BB * CKd) return;
  const int bc = idx >> 2;
  const int k  = idx & 3;
  float acc = t0b[k];
#pragma unroll
  for (int j = 0; j < 4; ++j) acc += xin[bc*4 + j] * t0w[k*4 + j];
  xout[idx] = acc;
}

__global__ __launch_bounds__(256) void recon_kernel(
    const float* __restrict__ xin, const float* __restrict__ UsL,
    const float* __restrict__ UdL, float* __restrict__ xout,
    int n, int lg, const float* __restrict__ rc_e, const float* __restrict__ rc_o)
{
  const int idx = blockIdx.x * 256 + threadIdx.x;
  if (idx >= BB * n) return;
  const int b = idx >> lg;
  const int t = idx & (n - 1);
  const size_t ro = ((size_t)b * n + t) * CKd;
  float xv[16], uv[16], dv[16];
#pragma unroll
  for (int q = 0; q < 4; ++q) {
    const float4 a = reinterpret_cast<const float4*>(xin + ro)[q];
    const float4 u = reinterpret_cast<const float4*>(UsL + ro)[q];
    const float4 d = reinterpret_cast<const float4*>(UdL + ro)[q];
    xv[q*4]=a.x; xv[q*4+1]=a.y; xv[q*4+2]=a.z; xv[q*4+3]=a.w;
    uv[q*4]=u.x; uv[q*4+1]=u.y; uv[q*4+2]=u.z; uv[q*4+3]=u.w;
    dv[q*4]=d.x; dv[q*4+1]=d.y; dv[q*4+2]=d.z; dv[q*4+3]=d.w;
  }
  float xe[16], xo[16];
#pragma unroll
  for (int c = 0; c < 4; ++c) {
    float xc[8];
#pragma unroll
    for (int m = 0; m < 4; ++m) { xc[m] = xv[c*4+m] + uv[c*4+m]; xc[4+m] = dv[c*4+m]; }
#pragma unroll
    for (int k = 0; k < 4; ++k) {
      float ae = 0.f, ao = 0.f;
#pragma unroll
      for (int m = 0; m < 8; ++m) { ae += xc[m] * rc_e[m*4+k]; ao += xc[m] * rc_o[m*4+k]; }
      xe[c*4+k] = ae; xo[c*4+k] = ao;
    }
  }
  float4* out = reinterpret_cast<float4*>(xout + ((size_t)b * (2*(size_t)n) + 2*(size_t)t) * CKd);
#pragma unroll
  for (int q = 0; q < 4; ++q) {
    out[q]   = make_float4(xe[q*4], xe[q*4+1], xe[q*4+2], xe[q*4+3]);
    out[4+q] = make_float4(xo[q*4], xo[q*4+1], xo[q*4+2], xo[q*4+3]);
  }
}

// ---------------------------------------------------------------------------
extern "C" void kernel_launch(void* const* d_in, const int* in_sizes, int n_in,
                              void* d_out, int out_size, void* d_ws, size_t ws_size,
                              hipStream_t stream)
{
  const float* x    = (const float*)d_in[0];
  const float* ec_s = (const float*)d_in[1];
  const float* ec_d = (const float*)d_in[2];
  const float* rc_e = (const float*)d_in[3];
  const float* rc_o = (const float*)d_in[4];
  const float* t0w  = (const float*)d_in[5];
  const float* t0b  = (const float*)d_in[6];
  const float* wAre = (const float*)d_in[7];
  const float* wAim = (const float*)d_in[8];
  const float* wBre = (const float*)d_in[9];
  const float* wBim = (const float*)d_in[10];
  const float* wCre = (const float*)d_in[11];
  const float* wCim = (const float*)d_in[12];

  float* ws = (float*)d_ws;
  const size_t XS_ELEMS = (size_t)BB * (NTOT/2) * CKd;   // 4,194,304
  const size_t U_ELEMS  = (size_t)BB * (NTOT - 1) * CKd; // 8,388,096
  const size_t F_ELEMS  = (size_t)BB * CKd * 64 * 2;     // 65,536
  float* xsA = ws;
  float* xsB = xsA + XS_ELEMS;
  float* UdS = xsB + XS_ELEMS;
  float* UsS = UdS + U_ELEMS;
  float* Fd  = UsS + U_ELEMS;
  float* Fx  = Fd + F_ELEMS;
  float* Gud = Fx + F_ELEMS;
  float* Gus = Gud + F_ELEMS;
  float* G4  = Gud;            // big path: G4 (2*F_ELEMS) aliases Gud+Gus

  float* udl[NLEV]; float* usl[NLEV]; int nlv[NLEV];

  // single upfront zero of the atomic targets; mix re-zeros per level
  hipMemsetAsync(Fd, 0, 2 * F_ELEMS * sizeof(float), stream);

  // ---- decomposition ----
  const float* cur = x;
  float* nxt = xsA;
  size_t uoff = 0;
  int nhalf = NTOT / 2;
  for (int j = 0; j < NLEV; ++j, nhalf >>= 1) {
    const int l = (nhalf/2 + 1 < 64) ? (nhalf/2 + 1) : 64;
    udl[j] = UdS + uoff; usl[j] = UsS + uoff; nlv[j] = nhalf;
    if (nhalf >= 512) {
      fwd_big<<<dim3(BB, nhalf/512), 256, 0, stream>>>(cur, nxt, Fd, Fx, ec_s, ec_d, nhalf);
      mix_big<<<dim3(BB, 64), 32, 0, stream>>>(Fd, Fx, G4,
                                               wAre, wAim, wBre, wBim, wCre, wCim);
      inv_big<<<dim3(BB, nhalf/128), 256, 0, stream>>>(G4, udl[j], usl[j], nhalf);
    } else {
      const int S = (nhalf + 255) / 256;   // == 1 here
      fwd_kernel<<<dim3(BB, S), 256, 0, stream>>>(cur, nxt, Fd, Fx, ec_s, ec_d, nhalf, l);
      mix_kernel<<<dim3(BB, l), 32, 0, stream>>>(Fd, Fx, Gud, Gus,
                                                 wAre, wAim, wBre, wBim, wCre, wCim);
      inv_kernel<<<dim3(BB, S), 256, 0, stream>>>(Gud, Gus, udl[j], usl[j], nhalf, l);
    }
    uoff += (size_t)BB * nhalf * CKd;
    cur = nxt;
    nxt = (nxt == xsA) ? xsB : xsA;
  }

  // ---- coarsest-scale T0 ----
  t0_kernel<<<2, 256, 0, stream>>>(cur, nxt, t0w, t0b);
  cur = nxt;
  nxt = (nxt == xsA) ? xsB : xsA;

  // ---- reconstruction ----
  for (int i = NLEV - 1; i >= 0; --i) {
    const int n = nlv[i];
    int lg = 0; while ((1 << lg) < n) ++lg;
    float* out = (i == 0) ? (float*)d_out : nxt;
    const int total = BB * n;
    recon_kernel<<<(total + 255) / 256, 256, 0, stream>>>(cur, usl[i], udl[i], out,
                                                          n, lg, rc_e, rc_o);
    cur = out;
    nxt = (nxt == xsA) ? xsB : xsA;
  }
}